// Round 4
// baseline (178.532 us; speedup 1.0000x reference)
//
#include <hip/hip_runtime.h>
#include <hip/hip_bf16.h>
#include <stdint.h>

typedef unsigned short u16;
typedef signed char i8;

#define D_INNER 2048
#define D_OUTER 2048
#define MROWS   8192                 // B*S = 2*4096
#define W_ELEMS (D_OUTER * D_INNER)  // 4194304
#define NPART   1024                 // absmean partial blocks

// ---- gemm geometry: 256x256 tile, BK=128 i8, A-only LDS (2x32KB), B in regs ----
#define BM 256
#define BN 256
#define BK 128
#define NKT (D_INNER / BK)           // 16 K-tiles
#define LDS_TOTAL 65536              // 2 slots x 32KB (A only)

typedef __attribute__((ext_vector_type(4))) float f32x4;
typedef __attribute__((ext_vector_type(4))) int   i32x4;
typedef __attribute__((ext_vector_type(16))) int  i32x16;

// ------- 1) fused prep (UNCHANGED): RMSNorm rows -> i8 + |w| partials -------
__global__ __launch_bounds__(256) void prep_kernel(const float* __restrict__ x,
                            const float* __restrict__ g,
                            const float* __restrict__ w,
                            i8* __restrict__ xn, float* __restrict__ srow,
                            float* __restrict__ partials) {
  __shared__ float red[4];
  __shared__ float redm[4];
  int t = threadIdx.x;
  int lane = t & 63, wvi = t >> 6;

  if (blockIdx.x >= MROWS) {
    int p = blockIdx.x - MROWS;
    int base = p * 1024;
    float s = 0.f;
#pragma unroll
    for (int r = 0; r < 4; ++r) {
      f32x4 v = ((const f32x4*)w)[base + r * 256 + t];
      s += fabsf(v[0]) + fabsf(v[1]) + fabsf(v[2]) + fabsf(v[3]);
    }
    for (int off = 32; off; off >>= 1) s += __shfl_down(s, off, 64);
    if (lane == 0) red[wvi] = s;
    __syncthreads();
    if (t == 0) partials[p] = red[0] + red[1] + red[2] + red[3];
    return;
  }

  int row = blockIdx.x;
  const f32x4* xr = (const f32x4*)(x + (size_t)row * D_INNER);
  i8* xo = xn + (size_t)row * D_INNER;

  f32x4 v0 = __builtin_nontemporal_load(&xr[t]);
  f32x4 v1 = __builtin_nontemporal_load(&xr[t + 256]);
  const f32x4* gr = (const f32x4*)g;
  f32x4 g0 = gr[t], g1 = gr[t + 256];

  float s = v0[0]*v0[0] + v0[1]*v0[1] + v0[2]*v0[2] + v0[3]*v0[3]
          + v1[0]*v1[0] + v1[1]*v1[1] + v1[2]*v1[2] + v1[3]*v1[3];
  float m = fmaxf(fmaxf(fmaxf(fabsf(v0[0]*g0[0]), fabsf(v0[1]*g0[1])),
                        fmaxf(fabsf(v0[2]*g0[2]), fabsf(v0[3]*g0[3]))),
                  fmaxf(fmaxf(fabsf(v1[0]*g1[0]), fabsf(v1[1]*g1[1])),
                        fmaxf(fabsf(v1[2]*g1[2]), fabsf(v1[3]*g1[3]))));
  for (int off = 32; off; off >>= 1) {
    s += __shfl_down(s, off, 64);
    m = fmaxf(m, __shfl_down(m, off, 64));
  }
  if (lane == 0) { red[wvi] = s; redm[wvi] = m; }
  __syncthreads();
  float total = red[0] + red[1] + red[2] + red[3];
  float rmax  = fmaxf(fmaxf(redm[0], redm[1]), fmaxf(redm[2], redm[3]));
  float invr = 1.0f / sqrtf(total * (1.0f / (float)D_INNER) + 1e-6f);

  float amax = fmaxf(rmax * invr, 1e-12f);
  float step = amax * (1.0f / 127.0f);
  float qs   = 127.0f / amax;
  if (t == 0) srow[row] = step;

  char4 q0, q1;
  float qv;
  qv = fminf(127.f, fmaxf(-127.f, rintf(v0[0]*invr*g0[0]*qs))); q0.x = (i8)(int)qv;
  qv = fminf(127.f, fmaxf(-127.f, rintf(v0[1]*invr*g0[1]*qs))); q0.y = (i8)(int)qv;
  qv = fminf(127.f, fmaxf(-127.f, rintf(v0[2]*invr*g0[2]*qs))); q0.z = (i8)(int)qv;
  qv = fminf(127.f, fmaxf(-127.f, rintf(v0[3]*invr*g0[3]*qs))); q0.w = (i8)(int)qv;
  qv = fminf(127.f, fmaxf(-127.f, rintf(v1[0]*invr*g1[0]*qs))); q1.x = (i8)(int)qv;
  qv = fminf(127.f, fmaxf(-127.f, rintf(v1[1]*invr*g1[1]*qs))); q1.y = (i8)(int)qv;
  qv = fminf(127.f, fmaxf(-127.f, rintf(v1[2]*invr*g1[2]*qs))); q1.z = (i8)(int)qv;
  qv = fminf(127.f, fmaxf(-127.f, rintf(v1[3]*invr*g1[3]*qs))); q1.w = (i8)(int)qv;
  ((char4*)xo)[t]       = q0;
  ((char4*)xo)[t + 256] = q1;
}

// ------- 2) ternary quantize (UNCHANGED) -------
__global__ __launch_bounds__(256) void quant_kernel(const float* __restrict__ w,
                             const float* __restrict__ partials,
                             float* __restrict__ gamma_out, i8* __restrict__ wq) {
  f32x4 pv = ((const f32x4*)partials)[threadIdx.x];
  double d = (double)pv[0] + (double)pv[1] + (double)pv[2] + (double)pv[3];
  for (int off = 32; off; off >>= 1) d += __shfl_down(d, off, 64);
  __shared__ double red[4];
  int lane = threadIdx.x & 63, wvi = threadIdx.x >> 6;
  if (lane == 0) red[wvi] = d;
  __syncthreads();
  double total = red[0] + red[1] + red[2] + red[3];
  float gamma = (float)(total * (1.0 / (double)W_ELEMS));
  float inv = 1.0f / (gamma + 1e-8f);
  if (blockIdx.x == 0 && threadIdx.x == 0) *gamma_out = gamma;

  int tid = blockIdx.x * blockDim.x + threadIdx.x;
  int stride = gridDim.x * blockDim.x;
  for (int i = tid; i < W_ELEMS / 4; i += stride) {
    f32x4 v = ((const f32x4*)w)[i];
    char4 q;
    q.x = (i8)(int)fminf(1.f, fmaxf(-1.f, rintf(v[0] * inv)));
    q.y = (i8)(int)fminf(1.f, fmaxf(-1.f, rintf(v[1] * inv)));
    q.z = (i8)(int)fminf(1.f, fmaxf(-1.f, rintf(v[2] * inv)));
    q.w = (i8)(int)fminf(1.f, fmaxf(-1.f, rintf(v[3] * inv)));
    ((char4*)wq)[i] = q;
  }
}

// ------- 3) i8 GEMM: A-only LDS, B direct global->reg (L2-resident) -------
// LDS pipe was the round-3 bottleneck (512KB/iter vs 1024 MFMA-cyc). B moves
// to per-wave register fragments loaded straight from global (inline-asm
// global_load_dwordx4 so they participate in manual vmcnt counting), double-
// buffered one tile ahead. LDS now carries A only: 2 slots x 32KB, row-major
// [256][128B] with XOR-involution chunks; staged via 4 global_load_lds per
// thread per tile (linear dest, pre-permuted src). Per tile: one counted
// WAITVM(12) (A(t) landed; also covers B(t) which needs <=16) + 2 barriers;
// no mid-phase barriers needed since DMA targets the other slot.
// XCD swizzle: each XCD owns a 2MB B-slice (4 nb) x 8 mb -> B L2-resident.
#define GLDS(SRC, DST) __builtin_amdgcn_global_load_lds( \
    (const __attribute__((address_space(1))) void*)(SRC), \
    (__attribute__((address_space(3))) void*)(DST), 16, 0, 0)
#define WAITVM(N) asm volatile("s_waitcnt vmcnt(" #N ")")
#define BAR()     __builtin_amdgcn_s_barrier()
#define FENCE()   __builtin_amdgcn_sched_barrier(0)
#define LGKM0()   do { asm volatile("s_waitcnt lgkmcnt(0)"); FENCE(); } while (0)
#define BLOAD(DST, PTR, OFFS) \
  asm volatile("global_load_dwordx4 %0, %1, off offset:" OFFS \
               : "=v"(DST) : "v"(PTR))

__global__ __launch_bounds__(512, 2) void gemm_bt(const i8* __restrict__ A,
                                                  const i8* __restrict__ Bw,
                                                  const float* __restrict__ gamma_p,
                                                  const float* __restrict__ srow,
                                                  float* __restrict__ C) {
  extern __shared__ i8 lds[];   // 2 x 32KB A slots

  // B-resident XCD swizzle: xcd = f&7 owns nb in [ (xcd&1)*4, +4 ) (2MB B)
  // and mb in [ (xcd>>1)*8, +8 ) (A streams through L2).
  int f   = blockIdx.y * 8 + blockIdx.x;   // 0..255, x-fastest
  int xcd = f & 7;
  int gg  = f >> 3;                        // 0..31
  int nb  = (xcd & 1) * 4 + (gg & 3);      // 0..7
  int mb  = (xcd >> 1) * 8 + (gg >> 2);    // 0..31
  int bm0 = mb * BM;
  int bn0 = nb * BN;

  int tid  = threadIdx.x;
  int lane = tid & 63;
  int wv   = tid >> 6;          // 0..7
  int wr   = wv >> 2;           // 0..1 -> rows wr*128
  int wc   = wv & 3;            // 0..3 -> cols wc*64
  int l31  = lane & 31;
  int hi   = lane >> 5;

  const i8* Ag = A  + (size_t)bm0 * D_INNER;
  const i8* Bg = Bw + (size_t)bn0 * D_INNER;

  // A staging: per GLDS round r (0..3): row = r*64 + (tid>>3), chunk = tid&7,
  // src chunk XOR'd by row&7 (= (tid>>3)&7), dst linear tid*16 + r*8192.
  size_t a_src0 = (size_t)(tid >> 3) * D_INNER + (((tid & 7) ^ ((tid >> 3) & 7)) << 4);

  // B fragment pointers (advance +128/tile; ks*32 via asm imm offset)
  const i8* pB0 = Bg + (size_t)(wc * 64 +      l31) * D_INNER + hi * 16;
  const i8* pB1 = Bg + (size_t)(wc * 64 + 32 + l31) * D_INNER + hi * 16;

  int rdA = (wr * 128 + l31) * BK;                 // + ph*4096 + swz[ks]
  int swz[4];
#pragma unroll
  for (int ks = 0; ks < 4; ++ks)
    swz[ks] = (((ks << 1) | hi) ^ (l31 & 7)) << 4;

  i32x16 acc[4][2] = {};
  i32x4 bfrA[4][2], bfrB[4][2];

#define STAGE_A(T_, S_) do { \
    _Pragma("unroll") for (int r = 0; r < 4; ++r) \
      GLDS(Ag + a_src0 + (size_t)r * (64 * D_INNER) + (size_t)(T_) * BK, \
           lds + (S_) * 32768 + r * 8192 + tid * 16); \
  } while (0)

#define BLOAD8(NXT) do { \
    BLOAD(NXT[0][0], pB0, "0");  BLOAD(NXT[0][1], pB1, "0");  \
    BLOAD(NXT[1][0], pB0, "32"); BLOAD(NXT[1][1], pB1, "32"); \
    BLOAD(NXT[2][0], pB0, "64"); BLOAD(NXT[2][1], pB1, "64"); \
    BLOAD(NXT[3][0], pB0, "96"); BLOAD(NXT[3][1], pB1, "96"); \
  } while (0)

#define MFMA8(PH, CUR) do { \
    __builtin_amdgcn_s_setprio(1); \
    _Pragma("unroll") for (int ks = 0; ks < 4; ++ks) { \
      acc[PH][0] = __builtin_amdgcn_mfma_i32_32x32x32_i8(af_[ks], CUR[ks][0], acc[PH][0], 0, 0, 0); \
      acc[PH][1] = __builtin_amdgcn_mfma_i32_32x32x32_i8(af_[ks], CUR[ks][1], acc[PH][1], 0, 0, 0); \
    } \
    __builtin_amdgcn_s_setprio(0); \
  } while (0)

// One K-tile. Issue next tile's loads first (B:8 then A:4 -> the steady
// WAITVM(12) leaves exactly next-tile loads in flight), then wait+barrier,
// then 4 mi-phases of {4 ds_read_b128, lgkm0, 8 MFMA}. End barrier protects
// the slot read here from being DMA-overwritten by tile T_+2's stage.
#define TILE(T_, CUR, NXT, DO_STAGE, WAITSTMT) do { \
    if (DO_STAGE) { \
      BLOAD8(NXT); \
      STAGE_A((T_) + 1, ((T_) + 1) & 1); \
      pB0 += BK; pB1 += BK; \
    } \
    WAITSTMT; FENCE(); \
    BAR(); FENCE(); \
    { const i8* sl_ = lds + ((T_) & 1) * 32768; \
      _Pragma("unroll") for (int ph = 0; ph < 4; ++ph) { \
        i32x4 af_[4]; \
        _Pragma("unroll") for (int ks = 0; ks < 4; ++ks) \
          af_[ks] = *(const i32x4*)(sl_ + rdA + ph * 4096 + swz[ks]); \
        LGKM0(); \
        MFMA8(ph, CUR); \
      } } \
    BAR(); \
  } while (0)

  // prologue: B(0) -> bfrA, A(0) -> slot0; pointers then at tile 1
  BLOAD8(bfrA);
  STAGE_A(0, 0);
  pB0 += BK; pB1 += BK;

  for (int t = 0; t < 14; t += 2) {
    TILE(t,     bfrA, bfrB, 1, WAITVM(12));
    TILE(t + 1, bfrB, bfrA, 1, WAITVM(12));
  }
  TILE(14, bfrA, bfrB, 1, WAITVM(12));
  TILE(15, bfrB, bfrA, 0, WAITVM(0));

  // epilogue: C/D 32x32 layout: col = lane&31, row = (reg&3) + 8*(reg>>2) + 4*hi
  float gamma = *gamma_p;
  int colb = bn0 + wc * 64 + l31;
#pragma unroll
  for (int mi = 0; mi < 4; ++mi) {
    int rbase = bm0 + wr * 128 + mi * 32 + hi * 4;
    f32x4 sg[4];
#pragma unroll
    for (int q = 0; q < 4; ++q) {
      f32x4 sv = *(const f32x4*)(srow + rbase + q * 8);
      sg[q] = sv * gamma;
    }
#pragma unroll
    for (int nj = 0; nj < 2; ++nj) {
      i32x16 v = acc[mi][nj];
      float* cp = C + (size_t)rbase * D_OUTER + (colb + nj * 32);
#pragma unroll
      for (int q = 0; q < 4; ++q)
#pragma unroll
        for (int rr = 0; rr < 4; ++rr)
          cp[(size_t)(q * 8 + rr) * D_OUTER] = (float)v[q * 4 + rr] * sg[q][rr];
    }
  }
}

extern "C" void kernel_launch(void* const* d_in, const int* in_sizes, int n_in,
                              void* d_out, int out_size, void* d_ws, size_t ws_size,
                              hipStream_t stream) {
  const float* x = (const float*)d_in[0];   // [2,4096,2048]
  const float* w = (const float*)d_in[1];   // [2048,2048]
  const float* g = (const float*)d_in[2];   // [2048]
  float* out = (float*)d_out;               // [2,4096,2048] fp32

  float* gamma_p  = (float*)d_ws;                                  // 1 float
  float* partials = (float*)((char*)d_ws + 64);                    // 1024 floats
  float* srow     = (float*)((char*)d_ws + 8192);                  // 8192 floats
  i8* xn = (i8*)((char*)d_ws + 8192 + 32768);                      // 16 MB
  i8* wq = (i8*)((char*)d_ws + 8192 + 32768 + (size_t)MROWS * D_INNER);  // 4 MB

  static bool attr_set = false;
  if (!attr_set) {
    (void)hipFuncSetAttribute(reinterpret_cast<const void*>(&gemm_bt),
                              hipFuncAttributeMaxDynamicSharedMemorySize, LDS_TOTAL);
    attr_set = true;
  }

  prep_kernel<<<MROWS + NPART, 256, 0, stream>>>(x, g, w, xn, srow, partials);
  quant_kernel<<<2048, 256, 0, stream>>>(w, partials, gamma_p, wq);
  gemm_bt<<<dim3(8, 32), 512, LDS_TOTAL, stream>>>(xn, wq, gamma_p, srow, out);
}

// Round 5
// 164.735 us; speedup vs baseline: 1.0838x; 1.0838x over previous
//
#include <hip/hip_runtime.h>
#include <hip/hip_bf16.h>
#include <stdint.h>

typedef unsigned short u16;
typedef signed char i8;

#define D_INNER 2048
#define D_OUTER 2048
#define MROWS   8192                 // B*S = 2*4096
#define W_ELEMS (D_OUTER * D_INNER)  // 4194304
#define NPART   1024                 // absmean partial blocks

// ---- gemm geometry: 256x256 tile, BK=128 i8, 2 full slots (A+B), 1-deep DMA ----
#define BM 256
#define BN 256
#define BK 128
#define NKT (D_INNER / BK)           // 16 K-tiles
#define SLOT_BYTES 65536             // A 32KB + B 32KB
#define LDS_TOTAL  131072            // 2 slots

typedef __attribute__((ext_vector_type(4))) float f32x4;
typedef __attribute__((ext_vector_type(4))) int   i32x4;
typedef __attribute__((ext_vector_type(16))) int  i32x16;

// ------- 1) prep: RMSNorm one WAVE per row (no LDS/sync) + |w| partials -------
__global__ __launch_bounds__(256) void prep_kernel(const float* __restrict__ x,
                            const float* __restrict__ g,
                            const float* __restrict__ w,
                            i8* __restrict__ xn, float* __restrict__ srow,
                            float* __restrict__ partials) {
  int t = threadIdx.x;
  int lane = t & 63, wvi = t >> 6;

  if (blockIdx.x >= MROWS / 4) {
    // ---- absmean partial over w: 1024 blocks x 16KB ----
    __shared__ float red[4];
    int p = blockIdx.x - MROWS / 4;
    int base = p * 1024;
    float s = 0.f;
#pragma unroll
    for (int r = 0; r < 4; ++r) {
      f32x4 v = ((const f32x4*)w)[base + r * 256 + t];
      s += fabsf(v[0]) + fabsf(v[1]) + fabsf(v[2]) + fabsf(v[3]);
    }
    for (int off = 32; off; off >>= 1) s += __shfl_down(s, off, 64);
    if (lane == 0) red[wvi] = s;
    __syncthreads();
    if (t == 0) partials[p] = red[0] + red[1] + red[2] + red[3];
    return;
  }

  // ---- RMSNorm: one wave owns one row; 8 f32x4 per lane ----
  int row = blockIdx.x * 4 + wvi;
  const f32x4* xr = (const f32x4*)(x + (size_t)row * D_INNER);
  const f32x4* gr = (const f32x4*)g;
  i8* xo = xn + (size_t)row * D_INNER;

  f32x4 v[8], gv[8];
#pragma unroll
  for (int r = 0; r < 8; ++r) {
    v[r]  = __builtin_nontemporal_load(&xr[lane + r * 64]);
    gv[r] = gr[lane + r * 64];
  }
  float s = 0.f, m = 0.f;
#pragma unroll
  for (int r = 0; r < 8; ++r) {
    s += v[r][0]*v[r][0] + v[r][1]*v[r][1] + v[r][2]*v[r][2] + v[r][3]*v[r][3];
    m = fmaxf(m, fmaxf(fmaxf(fabsf(v[r][0]*gv[r][0]), fabsf(v[r][1]*gv[r][1])),
                       fmaxf(fabsf(v[r][2]*gv[r][2]), fabsf(v[r][3]*gv[r][3]))));
  }
#pragma unroll
  for (int off = 32; off; off >>= 1) {
    s += __shfl_xor(s, off, 64);
    m = fmaxf(m, __shfl_xor(m, off, 64));
  }
  float invr = 1.0f / sqrtf(s * (1.0f / (float)D_INNER) + 1e-6f);
  float amax = fmaxf(m * invr, 1e-12f);
  float step = amax * (1.0f / 127.0f);
  float qs   = 127.0f / amax;
  if (lane == 0) srow[row] = step;

#pragma unroll
  for (int r = 0; r < 8; ++r) {
    char4 q;
    float qv;
    qv = fminf(127.f, fmaxf(-127.f, rintf(v[r][0]*invr*gv[r][0]*qs))); q.x = (i8)(int)qv;
    qv = fminf(127.f, fmaxf(-127.f, rintf(v[r][1]*invr*gv[r][1]*qs))); q.y = (i8)(int)qv;
    qv = fminf(127.f, fmaxf(-127.f, rintf(v[r][2]*invr*gv[r][2]*qs))); q.z = (i8)(int)qv;
    qv = fminf(127.f, fmaxf(-127.f, rintf(v[r][3]*invr*gv[r][3]*qs))); q.w = (i8)(int)qv;
    ((char4*)xo)[lane + r * 64] = q;
  }
}

// ------- 2) ternary quantize (UNCHANGED) -------
__global__ __launch_bounds__(256) void quant_kernel(const float* __restrict__ w,
                             const float* __restrict__ partials,
                             float* __restrict__ gamma_out, i8* __restrict__ wq) {
  f32x4 pv = ((const f32x4*)partials)[threadIdx.x];
  double d = (double)pv[0] + (double)pv[1] + (double)pv[2] + (double)pv[3];
  for (int off = 32; off; off >>= 1) d += __shfl_down(d, off, 64);
  __shared__ double red[4];
  int lane = threadIdx.x & 63, wvi = threadIdx.x >> 6;
  if (lane == 0) red[wvi] = d;
  __syncthreads();
  double total = red[0] + red[1] + red[2] + red[3];
  float gamma = (float)(total * (1.0 / (double)W_ELEMS));
  float inv = 1.0f / (gamma + 1e-8f);
  if (blockIdx.x == 0 && threadIdx.x == 0) *gamma_out = gamma;

  int tid = blockIdx.x * blockDim.x + threadIdx.x;
  int stride = gridDim.x * blockDim.x;
  for (int i = tid; i < W_ELEMS / 4; i += stride) {
    f32x4 v = ((const f32x4*)w)[i];
    char4 q;
    q.x = (i8)(int)fminf(1.f, fmaxf(-1.f, rintf(v[0] * inv)));
    q.y = (i8)(int)fminf(1.f, fmaxf(-1.f, rintf(v[1] * inv)));
    q.z = (i8)(int)fminf(1.f, fmaxf(-1.f, rintf(v[2] * inv)));
    q.w = (i8)(int)fminf(1.f, fmaxf(-1.f, rintf(v[3] * inv)));
    ((char4*)wq)[i] = q;
  }
}

// ------- 3) i8 GEMM: 2-barrier/tile, full-tile DMA into the idle slot -------
// R3's win (8-phase) came with 8 barriers/tile lockstep because staging hit
// the live slot. Here both A (32KB) and B (32KB) stage as a FULL tile into
// the OTHER slot -> compute region (8 B-reads + 16 A-reads + 32 MFMA per
// wave) runs with NO internal barriers; compiler schedules lgkmcnt finely
// and waves drift to overlap LDS with MFMA. Per tile: BAR1 (slot s^1 free),
// 8 GLDS into s^1, counted WAITVM(8) (tile t landed; t+1 in flight), BAR2
// (publish), compute. LDS layouts/read swizzles identical to verified R3/R4.
#define GLDS(SRC, DST) __builtin_amdgcn_global_load_lds( \
    (const __attribute__((address_space(1))) void*)(SRC), \
    (__attribute__((address_space(3))) void*)(DST), 16, 0, 0)
#define WAITVM(N) asm volatile("s_waitcnt vmcnt(" #N ")")
#define BAR()     __builtin_amdgcn_s_barrier()
#define FENCE()   __builtin_amdgcn_sched_barrier(0)

__global__ __launch_bounds__(512, 2) void gemm_bt(const i8* __restrict__ A,
                                                  const i8* __restrict__ Bw,
                                                  const float* __restrict__ gamma_p,
                                                  const float* __restrict__ srow,
                                                  float* __restrict__ C) {
  extern __shared__ i8 lds[];   // slot s: A at s*65536, B at s*65536+32768

  int f   = blockIdx.y * 8 + blockIdx.x;   // 0..255, x-fastest
  int xcd = f & 7;
  int gg  = f >> 3;
  int orig = xcd * 32 + gg;
  int nb  = orig & 7;
  int mb  = orig >> 3;
  int bm0 = mb * BM;
  int bn0 = nb * BN;

  int tid  = threadIdx.x;
  int lane = tid & 63;
  int wv   = tid >> 6;          // 0..7
  int wr   = wv >> 2;           // 0..1 -> rows wr*128
  int wc   = wv & 3;            // 0..3 -> cols wc*64
  int l31  = lane & 31;
  int hi   = lane >> 5;

  const i8* Ag = A  + (size_t)bm0 * D_INNER;
  const i8* Bg = Bw + (size_t)bn0 * D_INNER;

  // staging decode (verified R3/R4): round r covers rows r*64+(tid>>3);
  // src chunk XOR'd by row&7; dst linear row*128 + chunk*16.
  size_t src0 = (size_t)(tid >> 3) * D_INNER + (((tid & 7) ^ ((tid >> 3) & 7)) << 4);
  int dst0 = tid * 16;

  // read addressing (verified R3/R4)
  int rdA = (wr * 128 + l31) * BK;                 // + ph*4096 + swz[ks]
  int rdB[2];
  rdB[0] = 32768 + (wc * 64 +      l31) * BK;
  rdB[1] = 32768 + (wc * 64 + 32 + l31) * BK;
  int swz[4];
#pragma unroll
  for (int ks = 0; ks < 4; ++ks)
    swz[ks] = (((ks << 1) | hi) ^ (l31 & 7)) << 4;

  i32x16 acc[4][2] = {};

#define STAGE_FULL(T_, S_) do { \
    _Pragma("unroll") for (int r = 0; r < 4; ++r) \
      GLDS(Ag + src0 + (size_t)r * (64 * D_INNER) + (size_t)(T_) * BK, \
           lds + (S_) * SLOT_BYTES + r * 8192 + dst0); \
    _Pragma("unroll") for (int r = 0; r < 4; ++r) \
      GLDS(Bg + src0 + (size_t)r * (64 * D_INNER) + (size_t)(T_) * BK, \
           lds + (S_) * SLOT_BYTES + 32768 + r * 8192 + dst0); \
  } while (0)

#define COMPUTE(T_) do { \
    const i8* sl_ = lds + ((T_) & 1) * SLOT_BYTES; \
    i32x4 bf_[4][2]; \
    _Pragma("unroll") for (int ks = 0; ks < 4; ++ks) \
      _Pragma("unroll") for (int nj = 0; nj < 2; ++nj) \
        bf_[ks][nj] = *(const i32x4*)(sl_ + rdB[nj] + swz[ks]); \
    _Pragma("unroll") for (int ph = 0; ph < 4; ++ph) { \
      i32x4 af_[4]; \
      _Pragma("unroll") for (int ks = 0; ks < 4; ++ks) \
        af_[ks] = *(const i32x4*)(sl_ + rdA + ph * 4096 + swz[ks]); \
      __builtin_amdgcn_s_setprio(1); \
      _Pragma("unroll") for (int ks = 0; ks < 4; ++ks) { \
        acc[ph][0] = __builtin_amdgcn_mfma_i32_32x32x32_i8(af_[ks], bf_[ks][0], acc[ph][0], 0, 0, 0); \
        acc[ph][1] = __builtin_amdgcn_mfma_i32_32x32x32_i8(af_[ks], bf_[ks][1], acc[ph][1], 0, 0, 0); \
      } \
      __builtin_amdgcn_s_setprio(0); \
    } \
  } while (0)

#define TILE(T_, DO_STAGE, WAITSTMT) do { \
    FENCE(); \
    BAR();                       /* all waves done reading slot (T_+1)&1 */ \
    FENCE(); \
    if (DO_STAGE) STAGE_FULL((T_) + 1, ((T_) + 1) & 1); \
    FENCE(); \
    WAITSTMT;                    /* tile T_'s 8 loads landed (this wave) */ \
    FENCE(); \
    BAR();                       /* publish: everyone's tile-T_ data in LDS */ \
    FENCE(); \
    COMPUTE(T_); \
  } while (0)

  STAGE_FULL(0, 0);

  for (int t = 0; t < NKT - 1; ++t)
    TILE(t, 1, WAITVM(8));
  TILE(NKT - 1, 0, WAITVM(0));

  // epilogue: C/D 32x32 layout: col = lane&31, row = (reg&3) + 8*(reg>>2) + 4*hi
  float gamma = *gamma_p;
  int colb = bn0 + wc * 64 + l31;
#pragma unroll
  for (int mi = 0; mi < 4; ++mi) {
    int rbase = bm0 + wr * 128 + mi * 32 + hi * 4;
    f32x4 sg[4];
#pragma unroll
    for (int q = 0; q < 4; ++q) {
      f32x4 sv = *(const f32x4*)(srow + rbase + q * 8);
      sg[q] = sv * gamma;
    }
#pragma unroll
    for (int nj = 0; nj < 2; ++nj) {
      i32x16 v = acc[mi][nj];
      float* cp = C + (size_t)rbase * D_OUTER + (colb + nj * 32);
#pragma unroll
      for (int q = 0; q < 4; ++q)
#pragma unroll
        for (int rr = 0; rr < 4; ++rr)
          cp[(size_t)(q * 8 + rr) * D_OUTER] = (float)v[q * 4 + rr] * sg[q][rr];
    }
  }
}

extern "C" void kernel_launch(void* const* d_in, const int* in_sizes, int n_in,
                              void* d_out, int out_size, void* d_ws, size_t ws_size,
                              hipStream_t stream) {
  const float* x = (const float*)d_in[0];   // [2,4096,2048]
  const float* w = (const float*)d_in[1];   // [2048,2048]
  const float* g = (const float*)d_in[2];   // [2048]
  float* out = (float*)d_out;               // [2,4096,2048] fp32

  float* gamma_p  = (float*)d_ws;                                  // 1 float
  float* partials = (float*)((char*)d_ws + 64);                    // 1024 floats
  float* srow     = (float*)((char*)d_ws + 8192);                  // 8192 floats
  i8* xn = (i8*)((char*)d_ws + 8192 + 32768);                      // 16 MB
  i8* wq = (i8*)((char*)d_ws + 8192 + 32768 + (size_t)MROWS * D_INNER);  // 4 MB

  static bool attr_set = false;
  if (!attr_set) {
    (void)hipFuncSetAttribute(reinterpret_cast<const void*>(&gemm_bt),
                              hipFuncAttributeMaxDynamicSharedMemorySize, LDS_TOTAL);
    attr_set = true;
  }

  prep_kernel<<<MROWS / 4 + NPART, 256, 0, stream>>>(x, g, w, xn, srow, partials);
  quant_kernel<<<2048, 256, 0, stream>>>(w, partials, gamma_p, wq);
  gemm_bt<<<dim3(8, 32), 512, LDS_TOTAL, stream>>>(xn, wq, gamma_p, srow, out);
}

// Round 6
// 161.914 us; speedup vs baseline: 1.1026x; 1.0174x over previous
//
#include <hip/hip_runtime.h>
#include <hip/hip_bf16.h>
#include <stdint.h>

typedef unsigned short u16;
typedef signed char i8;

#define D_INNER 2048
#define D_OUTER 2048
#define MROWS   8192                 // B*S = 2*4096
#define W_ELEMS (D_OUTER * D_INNER)  // 4194304
#define NPART   1024                 // absmean partial blocks

// ---- gemm geometry: 256x256 tile, BK=128 i8, 4 waves x (128x128) out ----
#define BM 256
#define BN 256
#define BK 128
#define NKT (D_INNER / BK)           // 16 K-tiles
#define SLOT_BYTES 65536             // A 32KB + B 32KB
#define LDS_TOTAL  131072            // 2 slots

typedef __attribute__((ext_vector_type(4))) float f32x4;
typedef __attribute__((ext_vector_type(4))) int   i32x4;
typedef __attribute__((ext_vector_type(16))) int  i32x16;

// ------- 1) prep (UNCHANGED from R5): RMSNorm one wave/row + |w| partials -------
__global__ __launch_bounds__(256) void prep_kernel(const float* __restrict__ x,
                            const float* __restrict__ g,
                            const float* __restrict__ w,
                            i8* __restrict__ xn, float* __restrict__ srow,
                            float* __restrict__ partials) {
  int t = threadIdx.x;
  int lane = t & 63, wvi = t >> 6;

  if (blockIdx.x >= MROWS / 4) {
    __shared__ float red[4];
    int p = blockIdx.x - MROWS / 4;
    int base = p * 1024;
    float s = 0.f;
#pragma unroll
    for (int r = 0; r < 4; ++r) {
      f32x4 v = ((const f32x4*)w)[base + r * 256 + t];
      s += fabsf(v[0]) + fabsf(v[1]) + fabsf(v[2]) + fabsf(v[3]);
    }
    for (int off = 32; off; off >>= 1) s += __shfl_down(s, off, 64);
    if (lane == 0) red[wvi] = s;
    __syncthreads();
    if (t == 0) partials[p] = red[0] + red[1] + red[2] + red[3];
    return;
  }

  int row = blockIdx.x * 4 + wvi;
  const f32x4* xr = (const f32x4*)(x + (size_t)row * D_INNER);
  const f32x4* gr = (const f32x4*)g;
  i8* xo = xn + (size_t)row * D_INNER;

  f32x4 v[8], gv[8];
#pragma unroll
  for (int r = 0; r < 8; ++r) {
    v[r]  = __builtin_nontemporal_load(&xr[lane + r * 64]);
    gv[r] = gr[lane + r * 64];
  }
  float s = 0.f, m = 0.f;
#pragma unroll
  for (int r = 0; r < 8; ++r) {
    s += v[r][0]*v[r][0] + v[r][1]*v[r][1] + v[r][2]*v[r][2] + v[r][3]*v[r][3];
    m = fmaxf(m, fmaxf(fmaxf(fabsf(v[r][0]*gv[r][0]), fabsf(v[r][1]*gv[r][1])),
                       fmaxf(fabsf(v[r][2]*gv[r][2]), fabsf(v[r][3]*gv[r][3]))));
  }
#pragma unroll
  for (int off = 32; off; off >>= 1) {
    s += __shfl_xor(s, off, 64);
    m = fmaxf(m, __shfl_xor(m, off, 64));
  }
  float invr = 1.0f / sqrtf(s * (1.0f / (float)D_INNER) + 1e-6f);
  float amax = fmaxf(m * invr, 1e-12f);
  float step = amax * (1.0f / 127.0f);
  float qs   = 127.0f / amax;
  if (lane == 0) srow[row] = step;

#pragma unroll
  for (int r = 0; r < 8; ++r) {
    char4 q;
    float qv;
    qv = fminf(127.f, fmaxf(-127.f, rintf(v[r][0]*invr*gv[r][0]*qs))); q.x = (i8)(int)qv;
    qv = fminf(127.f, fmaxf(-127.f, rintf(v[r][1]*invr*gv[r][1]*qs))); q.y = (i8)(int)qv;
    qv = fminf(127.f, fmaxf(-127.f, rintf(v[r][2]*invr*gv[r][2]*qs))); q.z = (i8)(int)qv;
    qv = fminf(127.f, fmaxf(-127.f, rintf(v[r][3]*invr*gv[r][3]*qs))); q.w = (i8)(int)qv;
    ((char4*)xo)[lane + r * 64] = q;
  }
}

// ------- 2) ternary quantize (UNCHANGED) -------
__global__ __launch_bounds__(256) void quant_kernel(const float* __restrict__ w,
                             const float* __restrict__ partials,
                             float* __restrict__ gamma_out, i8* __restrict__ wq) {
  f32x4 pv = ((const f32x4*)partials)[threadIdx.x];
  double d = (double)pv[0] + (double)pv[1] + (double)pv[2] + (double)pv[3];
  for (int off = 32; off; off >>= 1) d += __shfl_down(d, off, 64);
  __shared__ double red[4];
  int lane = threadIdx.x & 63, wvi = threadIdx.x >> 6;
  if (lane == 0) red[wvi] = d;
  __syncthreads();
  double total = red[0] + red[1] + red[2] + red[3];
  float gamma = (float)(total * (1.0 / (double)W_ELEMS));
  float inv = 1.0f / (gamma + 1e-8f);
  if (blockIdx.x == 0 && threadIdx.x == 0) *gamma_out = gamma;

  int tid = blockIdx.x * blockDim.x + threadIdx.x;
  int stride = gridDim.x * blockDim.x;
  for (int i = tid; i < W_ELEMS / 4; i += stride) {
    f32x4 v = ((const f32x4*)w)[i];
    char4 q;
    q.x = (i8)(int)fminf(1.f, fmaxf(-1.f, rintf(v[0] * inv)));
    q.y = (i8)(int)fminf(1.f, fmaxf(-1.f, rintf(v[1] * inv)));
    q.z = (i8)(int)fminf(1.f, fmaxf(-1.f, rintf(v[2] * inv)));
    q.w = (i8)(int)fminf(1.f, fmaxf(-1.f, rintf(v[3] * inv)));
    ((char4*)wq)[i] = q;
  }
}

// ------- 3) i8 GEMM: 4 waves x (128x128), B reg-held, 1 barrier/tile -------
// Serialized-sum model across R0-R5: time/tile ~ LDS-read-cycles + MFMA-cycles.
// Lever = read:MFMA ratio. 4 waves with 4x4 acc (256 VGPR) + B fragments held
// in regs for the whole tile: 32 reads/wave/tile (128/CU, was 192) for the
// same 2340 MFMA cycles. Full-slot double-buffer -> staging (16 GLDS/thread,
// distributed 6/6/4/0 over the 4 mi-phases) always targets the idle slot ->
// ZERO intra-tile barriers; one vmcnt(0)+barrier per tile (tile t+1 not yet
// issued at that point, so 0 == counted wait on tile t only; last batch was
// issued a full phase earlier). LDS layout/GLDS decode/swizzle = verified R3.
#define GLDS(SRC, DST) __builtin_amdgcn_global_load_lds( \
    (const __attribute__((address_space(1))) void*)(SRC), \
    (__attribute__((address_space(3))) void*)(DST), 16, 0, 0)
#define WAITVM(N) asm volatile("s_waitcnt vmcnt(" #N ")")
#define BAR()     __builtin_amdgcn_s_barrier()
#define FENCE()   __builtin_amdgcn_sched_barrier(0)

__global__ __launch_bounds__(256, 1) void gemm_bt(const i8* __restrict__ A,
                                                  const i8* __restrict__ Bw,
                                                  const float* __restrict__ gamma_p,
                                                  const float* __restrict__ srow,
                                                  float* __restrict__ C) {
  extern __shared__ i8 lds[];   // slot s: A at s*65536, B at s*65536+32768

  int f   = blockIdx.y * 8 + blockIdx.x;   // 0..255, x-fastest
  int xcd = f & 7;
  int gg  = f >> 3;
  int orig = xcd * 32 + gg;
  int nb  = orig & 7;
  int mb  = orig >> 3;
  int bm0 = mb * BM;
  int bn0 = nb * BN;

  int tid  = threadIdx.x;
  int lane = tid & 63;
  int wv   = tid >> 6;          // 0..3
  int wr   = wv >> 1;           // 0..1 -> rows wr*128
  int wc   = wv & 1;            // 0..1 -> cols wc*128
  int l31  = lane & 31;
  int hi   = lane >> 5;

  const i8* Ag = A  + (size_t)bm0 * D_INNER;
  const i8* Bg = Bw + (size_t)bn0 * D_INNER;

  // staging decode (verified): round rr covers rows rr*32+(tid>>3);
  // src chunk XOR'd by row&7 (== (tid>>3)&7); dst linear rr*4096 + tid*16.
  size_t srcx = (size_t)(tid >> 3) * D_INNER + (((tid & 7) ^ ((tid >> 3) & 7)) << 4);

  // read addressing (verified formulas; row&7 == l31&7 everywhere)
  int rdA = (wr * 128 + l31) * BK;            // + mi*4096 + swz[ks]
  int rdB = 32768 + (wc * 128 + l31) * BK;    // + nj*4096 + swz[ks]
  int swz[4];
#pragma unroll
  for (int ks = 0; ks < 4; ++ks)
    swz[ks] = (((ks << 1) | hi) ^ (l31 & 7)) << 4;

  i32x16 acc[4][4] = {};
  i32x4 bf_[4][4];

#define GLDS_A(T_, RR, S_) \
    GLDS(Ag + srcx + (size_t)(RR) * (32 * D_INNER) + (size_t)(T_) * BK, \
         lds + (S_) * SLOT_BYTES + (RR) * 4096 + tid * 16)
#define GLDS_B(T_, RR, S_) \
    GLDS(Bg + srcx + (size_t)(RR) * (32 * D_INNER) + (size_t)(T_) * BK, \
         lds + (S_) * SLOT_BYTES + 32768 + (RR) * 4096 + tid * 16)

#define PHASE(T_, P_, DS_) do { \
    if (DS_) { \
      if ((P_) == 0) { GLDS_A(T_+1, 0, (T_+1)&1); GLDS_A(T_+1, 1, (T_+1)&1); \
                       GLDS_A(T_+1, 2, (T_+1)&1); GLDS_B(T_+1, 0, (T_+1)&1); \
                       GLDS_B(T_+1, 1, (T_+1)&1); GLDS_B(T_+1, 2, (T_+1)&1); } \
      if ((P_) == 1) { GLDS_A(T_+1, 3, (T_+1)&1); GLDS_A(T_+1, 4, (T_+1)&1); \
                       GLDS_A(T_+1, 5, (T_+1)&1); GLDS_B(T_+1, 3, (T_+1)&1); \
                       GLDS_B(T_+1, 4, (T_+1)&1); GLDS_B(T_+1, 5, (T_+1)&1); } \
      if ((P_) == 2) { GLDS_A(T_+1, 6, (T_+1)&1); GLDS_A(T_+1, 7, (T_+1)&1); \
                       GLDS_B(T_+1, 6, (T_+1)&1); GLDS_B(T_+1, 7, (T_+1)&1); } \
    } \
    const i8* sl_ = lds + ((T_) & 1) * SLOT_BYTES; \
    if ((P_) == 0) { \
      _Pragma("unroll") for (int ks = 0; ks < 4; ++ks) \
        _Pragma("unroll") for (int nj = 0; nj < 4; ++nj) \
          bf_[ks][nj] = *(const i32x4*)(sl_ + rdB + nj * 4096 + swz[ks]); \
    } \
    i32x4 af_[4]; \
    _Pragma("unroll") for (int ks = 0; ks < 4; ++ks) \
      af_[ks] = *(const i32x4*)(sl_ + rdA + (P_) * 4096 + swz[ks]); \
    __builtin_amdgcn_s_setprio(1); \
    _Pragma("unroll") for (int ks = 0; ks < 4; ++ks) \
      _Pragma("unroll") for (int nj = 0; nj < 4; ++nj) \
        acc[P_][nj] = __builtin_amdgcn_mfma_i32_32x32x32_i8(af_[ks], bf_[ks][nj], acc[P_][nj], 0, 0, 0); \
    __builtin_amdgcn_s_setprio(0); \
  } while (0)

  // prologue: full tile 0 into slot 0
#pragma unroll
  for (int rr = 0; rr < 8; ++rr) { GLDS_A(0, rr, 0); GLDS_B(0, rr, 0); }

  for (int t = 0; t < NKT; ++t) {
    WAITVM(0);                 // tile t landed (t+1 not yet issued)
    FENCE();
    BAR();                     // publish across waves; slot (t+1)&1 free
    FENCE();
    if (t < NKT - 1) {
      PHASE(t, 0, 1); PHASE(t, 1, 1); PHASE(t, 2, 1); PHASE(t, 3, 1);
    } else {
      PHASE(t, 0, 0); PHASE(t, 1, 0); PHASE(t, 2, 0); PHASE(t, 3, 0);
    }
  }

  // epilogue: C/D 32x32 layout: col = lane&31, row = (reg&3) + 8*(reg>>2) + 4*hi
  float gamma = *gamma_p;
#pragma unroll
  for (int mi = 0; mi < 4; ++mi) {
    int rbase = bm0 + wr * 128 + mi * 32 + hi * 4;
    f32x4 sg[4];
#pragma unroll
    for (int q = 0; q < 4; ++q) {
      f32x4 sv = *(const f32x4*)(srow + rbase + q * 8);
      sg[q] = sv * gamma;
    }
#pragma unroll
    for (int nj = 0; nj < 4; ++nj) {
      int colb = bn0 + wc * 128 + nj * 32 + l31;
      i32x16 v = acc[mi][nj];
      float* cp = C + (size_t)rbase * D_OUTER + colb;
#pragma unroll
      for (int q = 0; q < 4; ++q)
#pragma unroll
        for (int rr = 0; rr < 4; ++rr)
          cp[(size_t)(q * 8 + rr) * D_OUTER] = (float)v[q * 4 + rr] * sg[q][rr];
    }
  }
}

extern "C" void kernel_launch(void* const* d_in, const int* in_sizes, int n_in,
                              void* d_out, int out_size, void* d_ws, size_t ws_size,
                              hipStream_t stream) {
  const float* x = (const float*)d_in[0];   // [2,4096,2048]
  const float* w = (const float*)d_in[1];   // [2048,2048]
  const float* g = (const float*)d_in[2];   // [2048]
  float* out = (float*)d_out;               // [2,4096,2048] fp32

  float* gamma_p  = (float*)d_ws;                                  // 1 float
  float* partials = (float*)((char*)d_ws + 64);                    // 1024 floats
  float* srow     = (float*)((char*)d_ws + 8192);                  // 8192 floats
  i8* xn = (i8*)((char*)d_ws + 8192 + 32768);                      // 16 MB
  i8* wq = (i8*)((char*)d_ws + 8192 + 32768 + (size_t)MROWS * D_INNER);  // 4 MB

  static bool attr_set = false;
  if (!attr_set) {
    (void)hipFuncSetAttribute(reinterpret_cast<const void*>(&gemm_bt),
                              hipFuncAttributeMaxDynamicSharedMemorySize, LDS_TOTAL);
    attr_set = true;
  }

  prep_kernel<<<MROWS / 4 + NPART, 256, 0, stream>>>(x, g, w, xn, srow, partials);
  quant_kernel<<<2048, 256, 0, stream>>>(w, partials, gamma_p, wq);
  gemm_bt<<<dim3(8, 32), 256, LDS_TOTAL, stream>>>(xn, wq, gamma_p, srow, out);
}